// Round 4
// baseline (1404.166 us; speedup 1.0000x reference)
//
#include <hip/hip_runtime.h>

#define LVL 8
#define C 8192
#define D 128
#define P 8
#define F 4
#define K 4
#define S 4
#define NF 16384
#define NTOT (LVL*C)   // 65536

typedef __bf16 bf16;
typedef bf16 bf16x4 __attribute__((ext_vector_type(4)));
typedef bf16 bf16x8 __attribute__((ext_vector_type(8)));
typedef float f32x4 __attribute__((ext_vector_type(4)));

__device__ __forceinline__ f32x4 mfma16(bf16x8 a, bf16x8 b, f32x4 c) {
  return __builtin_amdgcn_mfma_f32_16x16x32_bf16(a, b, c, 0, 0, 0);
}
__device__ __forceinline__ bf16x4 b4(f32x4 v) {
  bf16x4 r; r[0]=(bf16)v[0]; r[1]=(bf16)v[1]; r[2]=(bf16)v[2]; r[3]=(bf16)v[3]; return r;
}
__device__ __forceinline__ float sigm(float x) { return __builtin_amdgcn_rcpf(1.f + __expf(-x)); }
__device__ __forceinline__ float tanh_(float x) { return 1.f - 2.f*__builtin_amdgcn_rcpf(1.f + __expf(2.f*x)); }

// ---- dtype-flexible accessors (f=1: float32 storage, f=0: bf16 storage) ----
__device__ __forceinline__ float ldf(const void* b, long i, int f) {
  return f ? ((const float*)b)[i] : (float)((const bf16*)b)[i];
}
__device__ __forceinline__ bf16x8 ldx8(const void* b, long i, int f) {
  if (f) {
    f32x4 a = *(const f32x4*)((const float*)b + i);
    f32x4 c = *(const f32x4*)((const float*)b + i + 4);
    bf16x8 r;
    r[0]=(bf16)a[0]; r[1]=(bf16)a[1]; r[2]=(bf16)a[2]; r[3]=(bf16)a[3];
    r[4]=(bf16)c[0]; r[5]=(bf16)c[1]; r[6]=(bf16)c[2]; r[7]=(bf16)c[3];
    return r;
  }
  return *(const bf16x8*)((const bf16*)b + i);
}
__device__ __forceinline__ f32x4 ld4f(const void* b, long i, int f) {
  if (f) return *(const f32x4*)((const float*)b + i);
  bf16x4 t = *(const bf16x4*)((const bf16*)b + i);
  f32x4 r; r[0]=(float)t[0]; r[1]=(float)t[1]; r[2]=(float)t[2]; r[3]=(float)t[3]; return r;
}
__device__ __forceinline__ void st4(void* b, long i, int f, f32x4 v) {
  if (f) *(f32x4*)((float*)b + i) = v;
  else   *(bf16x4*)((bf16*)b + i) = b4(v);
}

// ---- per-phase weight/bias fragment loads -------------------------------
__device__ __forceinline__ void load_wb(const bf16* Ut, const bf16* Wt, const float* b2,
                                        int w, int l15, int quad, int gc,
                                        bf16x8 (&AU)[3][4], bf16x8 (&AW)[3][4],
                                        f32x4& zb, f32x4& rb, f32x4& nbx, f32x4& nbh) {
#pragma unroll
  for (int tr = 0; tr < 3; tr++)
#pragma unroll
    for (int kt = 0; kt < 4; kt++) {
      size_t o = (size_t)(tr*128 + w*16 + l15)*128 + kt*32 + quad*8;
      AU[tr][kt] = *(const bf16x8*)&Ut[o];
      AW[tr][kt] = *(const bf16x8*)&Wt[o];
    }
  zb  = *(const f32x4*)&b2[0*128 + gc];
  rb  = *(const f32x4*)&b2[1*128 + gc];
  nbx = *(const f32x4*)&b2[2*128 + gc];
  nbh = *(const f32x4*)&b2[3*128 + gc];
}

// ---------------------------------------------------------------------------
// One GRU phase: T steps over up to NT*16 sequences resident in LDS.
// x rows supplied by src(t) per staging thread (row prow, 16B chunk pc8),
// depth-2 prefetch pipeline; one barrier per step. Returns final-h buffer id.
// ---------------------------------------------------------------------------
template<int NT, typename SRC>
__device__ __forceinline__ int gru_phase(int T, bool active, int tid, int prow, int pc8,
                                         int l15, int quad, int gc,
                                         const bf16x8 (&AU)[3][4], const bf16x8 (&AW)[3][4],
                                         f32x4 zb, f32x4 rb, f32x4 nbx, f32x4 nbh,
                                         bf16 (*hT)[32][136], bf16 (*xT)[32][136],
                                         f32x4 (&h)[NT], SRC&& src) {
#pragma unroll
  for (int nt = 0; nt < NT; nt++) { h[nt][0]=0.f; h[nt][1]=0.f; h[nt][2]=0.f; h[nt][3]=0.f; }
  { int* zp = (int*)&hT[0][0][0];
    for (int i = tid; i < 32*136/2; i += 512) zp[i] = 0; }
  if (active) { bf16x8 x0 = src(0); *(bf16x8*)&xT[0][prow][pc8] = x0; }
  __syncthreads();

  bf16x8 xnext;
  if (active && T > 1) xnext = src(1);

  int buf = 0;
  for (int t = 0; t < T; t++) {
    bf16x8 xnn = xnext;
    if (active && t + 2 < T) xnn = src(t + 2);

    f32x4 aZ[NT], aR[NT], aNx[NT], aNh[NT];
#pragma unroll
    for (int nt = 0; nt < NT; nt++) { aZ[nt]=zb; aR[nt]=rb; aNx[nt]=nbx; aNh[nt]=nbh; }

    const int xb = t & 1;
#pragma unroll
    for (int kt = 0; kt < 4; kt++) {
      bf16x8 Bh[NT], Bx[NT];
#pragma unroll
      for (int nt = 0; nt < NT; nt++) {
        Bh[nt] = *(const bf16x8*)&hT[buf][nt*16 + l15][kt*32 + quad*8];
        Bx[nt] = *(const bf16x8*)&xT[xb][nt*16 + l15][kt*32 + quad*8];
      }
#pragma unroll
      for (int nt = 0; nt < NT; nt++) {
        aZ[nt]  = mfma16(AU[0][kt], Bh[nt], aZ[nt]);
        aZ[nt]  = mfma16(AW[0][kt], Bx[nt], aZ[nt]);
        aR[nt]  = mfma16(AU[1][kt], Bh[nt], aR[nt]);
        aR[nt]  = mfma16(AW[1][kt], Bx[nt], aR[nt]);
        aNh[nt] = mfma16(AU[2][kt], Bh[nt], aNh[nt]);
        aNx[nt] = mfma16(AW[2][kt], Bx[nt], aNx[nt]);
      }
    }

#pragma unroll
    for (int nt = 0; nt < NT; nt++) {
      f32x4 hn = h[nt];
#pragma unroll
      for (int i = 0; i < 4; i++) {
        float z = sigm(aZ[nt][i]);
        float r = sigm(aR[nt][i]);
        float n = tanh_(aNx[nt][i] + r*aNh[nt][i]);
        hn[i] = z*hn[i] + (1.f - z)*n;
      }
      h[nt] = hn;
      *(bf16x4*)&hT[1-buf][nt*16 + l15][gc] = b4(hn);
    }
    if (active && t + 1 < T) *(bf16x8*)&xT[(t+1)&1][prow][pc8] = xnext;
    __syncthreads();
    xnext = xnn;
    buf ^= 1;
  }
  return buf;   // final h^T lives in hT[buf]
}

// ---------------------------------------------------------------------------
// Whole-level megakernel: per block = 8 classes.
//   Phase A: fn GRU (32 seqs, T=5) + fe epilogue ([h|table[ret]]@W_fn)
//            -> memfn global + feT LDS
//   Phase B: member GRU (8 seqs, T=13; steps 9-12 read feT)  [mode==0]
//   Phase C: super GRU (8 seqs, T=5; step 4 reads member h)  -> table level l
// mode==1 (global fns): phase A only, 32 fns/block.
// ---------------------------------------------------------------------------
struct LArgs {
  const void* ep; const void* em;
  const int *fpi, *fri, *ppi, *spi;
  long feb;      // fe output element base in d_out
  long tab_eb;   // table-level output element base
  int mode;
};

__global__ __launch_bounds__(512, 1) void level_kernel(LArgs a,
    const bf16* __restrict__ pUt, const bf16* __restrict__ pWt, const float* __restrict__ b2p,
    const bf16* __restrict__ mUt, const bf16* __restrict__ mWt, const float* __restrict__ b2m,
    const bf16* __restrict__ sUt, const bf16* __restrict__ sWt, const float* __restrict__ b2s,
    const bf16* __restrict__ wtT, void* dout, const int* __restrict__ flagp) {
  __shared__ __align__(16) bf16 hT[2][32][136];
  __shared__ __align__(16) bf16 xT[2][32][136];
  __shared__ __align__(16) bf16 feT[32][136];
  const int f = *flagp;
  const int tid = threadIdx.x;
  const int w = tid >> 6, l15 = tid & 15, quad = (tid & 63) >> 4;
  const int gc = w*16 + quad*4;
  const int prow = tid >> 4, pc8 = (tid & 15) * 8;
  const long fnrow0 = (long)blockIdx.x * 32;
  const long cls0 = (long)blockIdx.x * 8;

  bf16x8 AU[3][4], AW[3][4];
  f32x4 zb, rb, nbx, nbh;
  load_wb(pUt, pWt, b2p, w, l15, quad, gc, AU, AW, zb, rb, nbx, nbh);

  int fidx[4];
#pragma unroll
  for (int j = 0; j < 4; j++) fidx[j] = a.fpi[(fnrow0 + prow)*K + j];

  // ---- Phase A: fn GRU ----
  f32x4 h2[2];
  int bufF = gru_phase<2>(5, true, tid, prow, pc8, l15, quad, gc, AU, AW, zb, rb, nbx, nbh,
      hT, xT, h2,
      [&](int t) -> bf16x8 {
        if (t == 0) return ldx8(a.ep, pc8, f);
        return ldx8(dout, (long)fidx[t-1]*128 + pc8, f);
      });

  // fe epilogue: [h | table[ret]] @ W_fn
  {
    long rr = (long)a.fri[fnrow0 + prow];
    bf16x8 rv = ldx8(dout, rr*128 + pc8, f);
    *(bf16x8*)&xT[0][prow][pc8] = rv;
  }
  __syncthreads();
  {
    f32x4 acc[2];
#pragma unroll
    for (int nt = 0; nt < 2; nt++) { acc[nt][0]=0.f; acc[nt][1]=0.f; acc[nt][2]=0.f; acc[nt][3]=0.f; }
#pragma unroll
    for (int kt = 0; kt < 8; kt++) {
      bf16x8 A = *(const bf16x8*)&wtT[(size_t)(w*16 + l15)*256 + kt*32 + quad*8];
#pragma unroll
      for (int nt = 0; nt < 2; nt++) {
        bf16x8 B = (kt < 4) ? *(const bf16x8*)&hT[bufF][nt*16 + l15][kt*32 + quad*8]
                            : *(const bf16x8*)&xT[0][nt*16 + l15][(kt-4)*32 + quad*8];
        acc[nt] = mfma16(A, B, acc[nt]);
      }
    }
#pragma unroll
    for (int nt = 0; nt < 2; nt++) {
      st4(dout, a.feb + (fnrow0 + nt*16 + l15)*128 + gc, f, acc[nt]);
      *(bf16x4*)&feT[nt*16 + l15][gc] = b4(acc[nt]);
    }
  }
  if (a.mode) return;
  __syncthreads();   // fe MFMA reads done before member phase rewrites hT/xT

  // ---- Phase B: member GRU ----
  load_wb(mUt, mWt, b2m, w, l15, quad, gc, AU, AW, zb, rb, nbx, nbh);
  const bool act8 = prow < 8;
  int midx[8];
  if (act8) {
#pragma unroll
    for (int j = 0; j < 8; j++) midx[j] = a.ppi[(cls0 + prow)*P + j];
  }
  f32x4 h1[1];
  int bufM = gru_phase<1>(13, act8, tid, prow, pc8, l15, quad, gc, AU, AW, zb, rb, nbx, nbh,
      hT, xT, h1,
      [&](int t) -> bf16x8 {
        if (t == 0) return ldx8(a.em, pc8, f);
        if (t <= 8) return ldx8(dout, (long)midx[t-1]*128 + pc8, f);
        return *(const bf16x8*)&feT[prow*4 + (t-9)][pc8];
      });

  // stash member h (B-layout rows 0..7) into feT for super step 4
  if (act8) {
    bf16x8 mv = *(const bf16x8*)&hT[bufM][prow][pc8];
    *(bf16x8*)&feT[prow][pc8] = mv;
  }
  __syncthreads();

  // ---- Phase C: super GRU ----
  load_wb(sUt, sWt, b2s, w, l15, quad, gc, AU, AW, zb, rb, nbx, nbh);
  int sidx[4];
  if (act8) {
#pragma unroll
    for (int j = 0; j < 4; j++) sidx[j] = a.spi[(cls0 + prow)*S + j];
  }
  gru_phase<1>(5, act8, tid, prow, pc8, l15, quad, gc, AU, AW, zb, rb, nbx, nbh,
      hT, xT, h1,
      [&](int t) -> bf16x8 {
        if (t < 4) return ldx8(dout, (long)sidx[t]*128 + pc8, f);
        return *(const bf16x8*)&feT[prow][pc8];
      });

  if (l15 < 8)
    st4(dout, a.tab_eb + (cls0 + l15)*128 + gc, f, h1[0]);
}

// ---------------------------------------------------------------------------
// dtype detect (wave-parallel), weight convert, level-0 init.
// ---------------------------------------------------------------------------
__global__ void detect_kernel(const void* be, int* flag) {
  const unsigned short* u = (const unsigned short*)be;
  int bad = 0;
  for (int k = threadIdx.x; k < 128; k += 64) {
    unsigned e = (u[k] >> 7) & 0xFF;
    if (e >= 128) bad = 1;
  }
  unsigned long long m = __ballot(bad);
  if (threadIdx.x == 0) *flag = (m != 0ULL) ? 1 : 0;
}

__global__ void convert_kernel(const void* pW, const void* pU, const void* mW, const void* mU,
                               const void* sW, const void* sU, const void* W_fn,
                               const void* pb, const void* mb, const void* sb,
                               bf16* pWt, bf16* pUt, bf16* mWt, bf16* mUt,
                               bf16* sWt, bf16* sUt, bf16* wtT,
                               float* b2p, float* b2m, float* b2s,
                               const int* flagp) {
  const int f = *flagp;
  int i = blockIdx.x*256 + threadIdx.x;
  const int TT = 384*128;
  if (i < 6*TT) {
    int which = i / TT, j = i - which*TT;
    int c = j >> 7, k = j & 127;
    const void* src = (which==0)?pW:(which==1)?pU:(which==2)?mW:(which==3)?mU:(which==4)?sW:sU;
    bf16* dst = (which==0)?pWt:(which==1)?pUt:(which==2)?mWt:(which==3)?mUt:(which==4)?sWt:sUt;
    dst[c*128 + k] = (bf16)ldf(src, (long)k*384 + c, f);
    return;
  }
  i -= 6*TT;
  if (i < 128*256) { int c = i >> 8, k = i & 255; wtT[c*256 + k] = (bf16)ldf(W_fn, (long)k*128 + c, f); return; }
  i -= 128*256;
  if (i < 3*512) {
    int which = i >> 9, j = i & 511;
    const void* b = (which==0)?pb:(which==1)?mb:sb;
    float* dst = (which==0)?b2p:(which==1)?b2m:b2s;
    int g = j >> 7, cc = j & 127;
    float v;
    if (g == 0)      v = ldf(b, cc, f)       + ldf(b, 384 + cc, f);
    else if (g == 1) v = ldf(b, 128 + cc, f) + ldf(b, 512 + cc, f);
    else if (g == 2) v = ldf(b, 256 + cc, f);
    else             v = ldf(b, 640 + cc, f);
    dst[j] = v;
  }
}

__global__ void level0_kernel(const int* __restrict__ basic_ids, const void* basic_emb,
                              void* out, const int* __restrict__ flagp) {
  const int f = *flagp;
  int i = blockIdx.x*256 + threadIdx.x;   // < C*32
  int row = i >> 5, c4 = (i & 31) * 4;
  f32x4 v = ld4f(basic_emb, (long)basic_ids[row]*128 + c4, f);
  st4(out, (long)row*128 + c4, f, v);
}

// ---------------------------------------------------------------------------
extern "C" void kernel_launch(void* const* d_in, const int* in_sizes, int n_in,
                              void* d_out, int out_size, void* d_ws, size_t ws_size,
                              hipStream_t stream) {
  const int* basic_ids      = (const int*)d_in[0];
  const int* prop_idx       = (const int*)d_in[1];
  const int* func_param_idx = (const int*)d_in[2];
  const int* func_ret_idx   = (const int*)d_in[3];
  const int* super_idx      = (const int*)d_in[4];
  const int* glob_param_idx = (const int*)d_in[5];
  const int* glob_ret_idx   = (const int*)d_in[6];
  const void* basic_emb     = d_in[7];
  const void* empty_params  = d_in[8];
  const void* empty_members = d_in[9];
  const void* W_fn = d_in[10];
  const void* pW = d_in[11]; const void* pU = d_in[12]; const void* pb = d_in[13];
  const void* mW = d_in[14]; const void* mU = d_in[15]; const void* mb = d_in[16];
  const void* sW = d_in[17]; const void* sU = d_in[18]; const void* sb = d_in[19];

  // d_out element layout: table [NTOT*128] | glob [NF*128] | memfn [7*C*F*128]
  const long GB = (long)NTOT*128;
  const long MB0 = GB + (long)NF*128;

  char* wp = (char*)d_ws;
  auto carve = [&](size_t bytes) { char* p = wp; wp += (bytes + 255) & ~(size_t)255; return p; };
  int*  flag = (int*)carve(256);
  bf16* pWt = (bf16*)carve(384*128*2);
  bf16* pUt = (bf16*)carve(384*128*2);
  bf16* mWt = (bf16*)carve(384*128*2);
  bf16* mUt = (bf16*)carve(384*128*2);
  bf16* sWt = (bf16*)carve(384*128*2);
  bf16* sUt = (bf16*)carve(384*128*2);
  bf16* wtT = (bf16*)carve(128*256*2);
  float* b2p = (float*)carve(512*4);
  float* b2m = (float*)carve(512*4);
  float* b2s = (float*)carve(512*4);

  detect_kernel<<<1, 64, 0, stream>>>(basic_emb, flag);
  {
    int total = 6*384*128 + 128*256 + 3*512;
    convert_kernel<<<(total + 255)/256, 256, 0, stream>>>(pW, pU, mW, mU, sW, sU, W_fn,
                                                          pb, mb, sb,
                                                          pWt, pUt, mWt, mUt, sWt, sUt, wtT,
                                                          b2p, b2m, b2s, flag);
  }
  level0_kernel<<<(C*32)/256, 256, 0, stream>>>(basic_ids, basic_emb, d_out, flag);

  for (int l = 1; l < LVL; l++) {
    LArgs a{};
    a.ep = empty_params; a.em = empty_members;
    a.fpi = func_param_idx + (size_t)(l-1)*C*F*K;
    a.fri = func_ret_idx   + (size_t)(l-1)*C*F;
    a.ppi = prop_idx       + (size_t)(l-1)*C*P;
    a.spi = super_idx      + (size_t)(l-1)*C*S;
    a.feb = MB0 + (long)(l-1)*C*F*128;
    a.tab_eb = (long)l*C*128;
    a.mode = 0;
    level_kernel<<<C/8, 512, 0, stream>>>(a, pUt, pWt, b2p, mUt, mWt, b2m,
                                          sUt, sWt, b2s, wtT, d_out, flag);
  }

  {
    LArgs a{};
    a.ep = empty_params; a.em = empty_members;
    a.fpi = glob_param_idx; a.fri = glob_ret_idx;
    a.ppi = glob_param_idx; a.spi = glob_param_idx;   // unused in mode 1
    a.feb = GB; a.tab_eb = 0;
    a.mode = 1;
    level_kernel<<<NF/32, 512, 0, stream>>>(a, pUt, pWt, b2p, mUt, mWt, b2m,
                                            sUt, sWt, b2s, wtT, d_out, flag);
  }
}